// Round 9
// baseline (115.701 us; speedup 1.0000x reference)
//
#include <hip/hip_runtime.h>
#include <cstddef>

// Problem constants
#define B_DIM 64
#define C_DIM 256
#define T_DIM 120
#define V_DIM 25
#define TV    3000                      // T_DIM * V_DIM
#define CTILE 16
#define NROWS (B_DIM * C_DIM)           // 16384 rows of TV floats
#define ROWF4 (TV / 4)                  // 750 float4 per row

// add_kernel geometry (R9): each thread owns ONE within-row phase (a 32 B
// pair of float4s at float offset pos = w8*8) across 8 rows spaced 2048
// apart. All ov addends preloaded to registers -> the streaming loop is a
// literal copy (2 loads, reg adds, 2 nt stores).
#define ABLOCKS 3000
#define ATHREADS 256
#define NTHREADS (ABLOCKS * ATHREADS)   // 768000
#define PAIRS_PER_ROW (ROWF4 / 2)       // 375
#define AROWSTEP (NTHREADS / PAIRS_PER_ROW)  // 2048 rows per k-step
#define KSTEPS (NROWS / AROWSTEP)       // 8 rows per thread, zero remainder

typedef float f4v __attribute__((ext_vector_type(4)));

// ---------------------------------------------------------------------------
// Kernel A: fold the two linear layers.
//   WcT[i][c] = sum_j Wo[c][j] * Wv[j][i]
//   bc[c]     = sum_i Wo[c][i] * bv[i] + bo[c]
// ---------------------------------------------------------------------------
__global__ __launch_bounds__(256) void make_wc(
    const float* __restrict__ Wo, const float* __restrict__ Wv,
    const float* __restrict__ bv, const float* __restrict__ bo,
    float* __restrict__ WcT, float* __restrict__ bc) {
  const int c = blockIdx.x;
  const int i = threadIdx.x;

  float acc = 0.0f;
#pragma unroll 8
  for (int j = 0; j < C_DIM; ++j) {
    acc = fmaf(Wo[c * C_DIM + j], Wv[j * C_DIM + i], acc);
  }
  WcT[i * C_DIM + c] = acc;

  __shared__ float red[C_DIM];
  red[i] = Wo[c * C_DIM + i] * bv[i];
  __syncthreads();
  for (int s = 128; s > 0; s >>= 1) {
    if (i < s) red[i] += red[i + s];
    __syncthreads();
  }
  if (i == 0) bc[c] = red[0] + bo[c];
}

// ---------------------------------------------------------------------------
// Kernel B: ov[b*C + c][t] = bc[c] + sum_i WcT[i][c] * y[b][i][t]
// grid = (B, C/CTILE), block = 256. y loads double-buffered; WcT wave-uniform.
// ---------------------------------------------------------------------------
__global__ __launch_bounds__(256) void ov_kernel(
    const float* __restrict__ y, const float* __restrict__ WcT,
    const float* __restrict__ bc, float* __restrict__ ov) {
  const int b   = blockIdx.x;
  const int c0  = blockIdx.y * CTILE;
  const int tid = threadIdx.x;
  const int chalf = tid >> 7;      // wave-uniform
  const int t     = tid & 127;
  if (t >= T_DIM) return;

  const int cb = __builtin_amdgcn_readfirstlane(c0 + chalf * 8);

  float acc[8];
#pragma unroll
  for (int cl = 0; cl < 8; ++cl) acc[cl] = bc[cb + cl];

  const float* yb = y + (size_t)b * C_DIM * T_DIM + t;

  float yv[8];
#pragma unroll
  for (int u = 0; u < 8; ++u) yv[u] = yb[(size_t)u * T_DIM];

#define FMA_GROUP(ibase)                                              \
  _Pragma("unroll")                                                   \
  for (int u = 0; u < 8; ++u) {                                       \
    const f4v* wr = (const f4v*)(WcT + ((ibase) + u) * C_DIM + cb);   \
    const f4v w0 = wr[0];                                             \
    const f4v w1 = wr[1];                                             \
    acc[0] = fmaf(w0.x, yv[u], acc[0]);                               \
    acc[1] = fmaf(w0.y, yv[u], acc[1]);                               \
    acc[2] = fmaf(w0.z, yv[u], acc[2]);                               \
    acc[3] = fmaf(w0.w, yv[u], acc[3]);                               \
    acc[4] = fmaf(w1.x, yv[u], acc[4]);                               \
    acc[5] = fmaf(w1.y, yv[u], acc[5]);                               \
    acc[6] = fmaf(w1.z, yv[u], acc[6]);                               \
    acc[7] = fmaf(w1.w, yv[u], acc[7]);                               \
  }

  for (int i = 0; i < C_DIM - 8; i += 8) {
    float yn[8];
#pragma unroll
    for (int u = 0; u < 8; ++u) yn[u] = yb[(size_t)(i + 8 + u) * T_DIM];
    FMA_GROUP(i)
#pragma unroll
    for (int u = 0; u < 8; ++u) yv[u] = yn[u];
  }
  FMA_GROUP(C_DIM - 8)
#undef FMA_GROUP

  float* ovp = ov + ((size_t)b * C_DIM + cb) * T_DIM + t;
#pragma unroll
  for (int cl = 0; cl < 8; ++cl) ovp[(size_t)cl * T_DIM] = acc[cl];
}

// ---------------------------------------------------------------------------
// Kernel C (R9): streaming z = x + addend, with ALL addends preloaded into
// registers. Each thread: fixed within-row phase pos = w8*8 (floats
// pos..pos+7), rows row0 + k*2048 for k = 0..7. 16 ov scalar loads happen
// ONCE up front; the loop body is 2 dwordx4 loads + reg adds + 2 nt stores
// (a pure copy pattern, 32 B contiguous per thread, 2 KB per wave).
// ---------------------------------------------------------------------------
__global__ __launch_bounds__(ATHREADS) void add_kernel(
    const float* __restrict__ x, const float* __restrict__ ov,
    float* __restrict__ z) {
  const int g    = blockIdx.x * ATHREADS + threadIdx.x;  // [0, NTHREADS)
  const int row0 = g / PAIRS_PER_ROW;                    // [0, AROWSTEP)
  const int w8   = g - row0 * PAIRS_PER_ROW;             // [0, 375)
  const int pos  = w8 * 8;
  const int t0   = pos / V_DIM;
  const int r    = pos - t0 * V_DIM;                     // 0..24

  // Component j (0..7) uses addend from t0+1 iff r + j >= 25 (j>=1 only).
  // Any crossing implies r >= 18, and then t0+1 <= 119 (in bounds).
  const int o1 = t0 + ((r >= 18) ? 1 : 0);
  const bool s1 = (r >= 24), s2 = (r >= 23), s3 = (r >= 22);
  const bool s4 = (r >= 21), s5 = (r >= 20), s6 = (r >= 19), s7 = (r >= 18);

  // Preload all addends (16 floats) into registers.
  float a0[KSTEPS], a1[KSTEPS];
#pragma unroll
  for (int k = 0; k < KSTEPS; ++k) {
    const float* o = ov + (size_t)(row0 + k * AROWSTEP) * T_DIM;
    a0[k] = o[t0];
    a1[k] = o[o1];
  }

  const f4v* __restrict__ xin  = (const f4v*)x;
  f4v* __restrict__       zout = (f4v*)z;

#pragma unroll
  for (int s = 0; s < 2; ++s) {
    f4v lo[4], hi[4];
#pragma unroll
    for (int kb = 0; kb < 4; ++kb) {
      const int k = s * 4 + kb;
      const size_t base = (size_t)(row0 + k * AROWSTEP) * ROWF4 + w8 * 2;
      lo[kb] = xin[base];
      hi[kb] = xin[base + 1];
    }
    // All 8 x-loads issued before any add/store.
    __builtin_amdgcn_sched_barrier(0);
#pragma unroll
    for (int kb = 0; kb < 4; ++kb) {
      const int k = s * 4 + kb;
      const size_t base = (size_t)(row0 + k * AROWSTEP) * ROWF4 + w8 * 2;
      f4v ol, oh;
      ol.x = lo[kb].x + a0[k];
      ol.y = lo[kb].y + (s1 ? a1[k] : a0[k]);
      ol.z = lo[kb].z + (s2 ? a1[k] : a0[k]);
      ol.w = lo[kb].w + (s3 ? a1[k] : a0[k]);
      oh.x = hi[kb].x + (s4 ? a1[k] : a0[k]);
      oh.y = hi[kb].y + (s5 ? a1[k] : a0[k]);
      oh.z = hi[kb].z + (s6 ? a1[k] : a0[k]);
      oh.w = hi[kb].w + (s7 ? a1[k] : a0[k]);
      __builtin_nontemporal_store(ol, &zout[base]);
      __builtin_nontemporal_store(oh, &zout[base + 1]);
    }
  }
}

// ---------------------------------------------------------------------------
extern "C" void kernel_launch(void* const* d_in, const int* in_sizes, int n_in,
                              void* d_out, int out_size, void* d_ws, size_t ws_size,
                              hipStream_t stream) {
  // setup_inputs order: x, y, Wq, bq, Wk, bk, Wv, bv, Wo, bo
  const float* x  = (const float*)d_in[0];
  const float* y  = (const float*)d_in[1];
  const float* Wv = (const float*)d_in[6];
  const float* bv = (const float*)d_in[7];
  const float* Wo = (const float*)d_in[8];
  const float* bo = (const float*)d_in[9];
  float* z = (float*)d_out;

  // ws layout: ov (B*C*T floats = 7.86 MB) | WcT (256 KiB) | bc (1 KiB)
  float* ov  = (float*)d_ws;
  float* WcT = ov + (size_t)NROWS * T_DIM;
  float* bc  = WcT + C_DIM * C_DIM;

  make_wc<<<dim3(C_DIM), dim3(C_DIM), 0, stream>>>(Wo, Wv, bv, bo, WcT, bc);

  ov_kernel<<<dim3(B_DIM, C_DIM / CTILE), dim3(256), 0, stream>>>(y, WcT, bc, ov);

  add_kernel<<<dim3(ABLOCKS), dim3(ATHREADS), 0, stream>>>(x, ov, z);
}

// Round 10
// 98.359 us; speedup vs baseline: 1.1763x; 1.1763x over previous
//
#include <hip/hip_runtime.h>
#include <cstddef>

// Problem constants
#define B_DIM 64
#define C_DIM 256
#define T_DIM 120
#define V_DIM 25
#define TV    3000                      // T_DIM * V_DIM
#define CTILE 16
#define NROWS (B_DIM * C_DIM)           // 16384 rows of TV floats
#define ROWF4 (TV / 4)                  // 750 float4 per row

// add_kernel geometry (R8's proven-dense mapping): thread g owns within-row
// f4 index w4 = g % 750 (consecutive lanes -> consecutive float4s) and rows
// row0 + m*2048 for m = 0..7.
#define ABLOCKS 6000
#define ATHREADS 256
#define ATOTAL (ABLOCKS * ATHREADS)     // 1,536,000 f4 = 750 * 2048 rows
#define AROWSTEP (ATOTAL / ROWF4)       // 2048 rows per step
#define MSTEPS (NROWS / AROWSTEP)       // 8 row-steps per thread
#define BATCH 4
#define SUPERS (MSTEPS / BATCH)         // 2

typedef float f4v __attribute__((ext_vector_type(4)));

// ---------------------------------------------------------------------------
// Kernel A: fold the two linear layers.
//   WcT[i][c] = sum_j Wo[c][j] * Wv[j][i]
//   bc[c]     = sum_i Wo[c][i] * bv[i] + bo[c]
// ---------------------------------------------------------------------------
__global__ __launch_bounds__(256) void make_wc(
    const float* __restrict__ Wo, const float* __restrict__ Wv,
    const float* __restrict__ bv, const float* __restrict__ bo,
    float* __restrict__ WcT, float* __restrict__ bc) {
  const int c = blockIdx.x;
  const int i = threadIdx.x;

  float acc = 0.0f;
#pragma unroll 8
  for (int j = 0; j < C_DIM; ++j) {
    acc = fmaf(Wo[c * C_DIM + j], Wv[j * C_DIM + i], acc);
  }
  WcT[i * C_DIM + c] = acc;

  __shared__ float red[C_DIM];
  red[i] = Wo[c * C_DIM + i] * bv[i];
  __syncthreads();
  for (int s = 128; s > 0; s >>= 1) {
    if (i < s) red[i] += red[i + s];
    __syncthreads();
  }
  if (i == 0) bc[c] = red[0] + bo[c];
}

// ---------------------------------------------------------------------------
// Kernel B: ov[b*C + c][t] = bc[c] + sum_i WcT[i][c] * y[b][i][t]
// grid = (B, C/CTILE), block = 256. y loads double-buffered; WcT wave-uniform.
// ---------------------------------------------------------------------------
__global__ __launch_bounds__(256) void ov_kernel(
    const float* __restrict__ y, const float* __restrict__ WcT,
    const float* __restrict__ bc, float* __restrict__ ov) {
  const int b   = blockIdx.x;
  const int c0  = blockIdx.y * CTILE;
  const int tid = threadIdx.x;
  const int chalf = tid >> 7;      // wave-uniform
  const int t     = tid & 127;
  if (t >= T_DIM) return;

  const int cb = __builtin_amdgcn_readfirstlane(c0 + chalf * 8);

  float acc[8];
#pragma unroll
  for (int cl = 0; cl < 8; ++cl) acc[cl] = bc[cb + cl];

  const float* yb = y + (size_t)b * C_DIM * T_DIM + t;

  float yv[8];
#pragma unroll
  for (int u = 0; u < 8; ++u) yv[u] = yb[(size_t)u * T_DIM];

#define FMA_GROUP(ibase)                                              \
  _Pragma("unroll")                                                   \
  for (int u = 0; u < 8; ++u) {                                       \
    const f4v* wr = (const f4v*)(WcT + ((ibase) + u) * C_DIM + cb);   \
    const f4v w0 = wr[0];                                             \
    const f4v w1 = wr[1];                                             \
    acc[0] = fmaf(w0.x, yv[u], acc[0]);                               \
    acc[1] = fmaf(w0.y, yv[u], acc[1]);                               \
    acc[2] = fmaf(w0.z, yv[u], acc[2]);                               \
    acc[3] = fmaf(w0.w, yv[u], acc[3]);                               \
    acc[4] = fmaf(w1.x, yv[u], acc[4]);                               \
    acc[5] = fmaf(w1.y, yv[u], acc[5]);                               \
    acc[6] = fmaf(w1.z, yv[u], acc[6]);                               \
    acc[7] = fmaf(w1.w, yv[u], acc[7]);                               \
  }

  for (int i = 0; i < C_DIM - 8; i += 8) {
    float yn[8];
#pragma unroll
    for (int u = 0; u < 8; ++u) yn[u] = yb[(size_t)(i + 8 + u) * T_DIM];
    FMA_GROUP(i)
#pragma unroll
    for (int u = 0; u < 8; ++u) yv[u] = yn[u];
  }
  FMA_GROUP(C_DIM - 8)
#undef FMA_GROUP

  float* ovp = ov + ((size_t)b * C_DIM + cb) * T_DIM + t;
#pragma unroll
  for (int cl = 0; cl < 8; ++cl) ovp[(size_t)cl * T_DIM] = acc[cl];
}

// ---------------------------------------------------------------------------
// Kernel C (R10): z = x + addend. R8's dense mapping, but the 16 addend
// floats are preloaded ONCE and pinned live with empty asm anchors so the
// compiler cannot rematerialize the ov loads inside the loop (R9 lesson:
// without the anchor it collapses to VGPR=32 and re-gathers). Steady-state
// loop body = 4 dwordx4 loads + reg adds + 4 nt dwordx4 stores. Pure copy.
// ---------------------------------------------------------------------------
__global__ __launch_bounds__(ATHREADS) void add_kernel(
    const float* __restrict__ x, const float* __restrict__ ov,
    float* __restrict__ z) {
  const int g    = blockIdx.x * ATHREADS + threadIdx.x;  // [0, ATOTAL)
  const int row0 = g / ROWF4;                            // [0, AROWSTEP)
  const int w4   = g - row0 * ROWF4;                     // [0, 750) dense
  const int pos  = w4 * 4;
  const int t0   = pos / V_DIM;
  const int r    = pos - t0 * V_DIM;                     // 0..24

  // Component j (1..3) needs t0+1's addend iff r + j >= 25.
  // s1 => s3 and s2 => s3, so o1 is valid whenever any select fires;
  // crossing implies pos+3 < 3000 so t0+1 <= 119 (in bounds).
  const bool s1 = (r + 1 >= V_DIM), s2 = (r + 2 >= V_DIM), s3 = (r + 3 >= V_DIM);
  const int  o1 = t0 + (s3 ? 1 : 0);

  // Preload all 16 addends and pin them live.
  float a0[MSTEPS], a1[MSTEPS];
#pragma unroll
  for (int m = 0; m < MSTEPS; ++m) {
    const float* o = ov + (size_t)(row0 + m * AROWSTEP) * T_DIM;
    a0[m] = o[t0];
    a1[m] = o[o1];
    asm volatile("" : "+v"(a0[m]), "+v"(a1[m]));  // forbid rematerialization
  }

  const f4v* __restrict__ xin  = (const f4v*)x;
  f4v* __restrict__       zout = (f4v*)z;

#pragma unroll
  for (int s = 0; s < SUPERS; ++s) {
    f4v xv[BATCH];
#pragma unroll
    for (int j = 0; j < BATCH; ++j)
      xv[j] = xin[(size_t)g + (size_t)(s * BATCH + j) * ATOTAL];

    // All 4 x-loads issued before any add/store below.
    __builtin_amdgcn_sched_barrier(0);

#pragma unroll
    for (int j = 0; j < BATCH; ++j) {
      const int m = s * BATCH + j;
      f4v o;
      o.x = xv[j].x + a0[m];
      o.y = xv[j].y + (s1 ? a1[m] : a0[m]);
      o.z = xv[j].z + (s2 ? a1[m] : a0[m]);
      o.w = xv[j].w + (s3 ? a1[m] : a0[m]);
      __builtin_nontemporal_store(o, &zout[(size_t)g + (size_t)m * ATOTAL]);
    }
  }
}

// ---------------------------------------------------------------------------
extern "C" void kernel_launch(void* const* d_in, const int* in_sizes, int n_in,
                              void* d_out, int out_size, void* d_ws, size_t ws_size,
                              hipStream_t stream) {
  // setup_inputs order: x, y, Wq, bq, Wk, bk, Wv, bv, Wo, bo
  const float* x  = (const float*)d_in[0];
  const float* y  = (const float*)d_in[1];
  const float* Wv = (const float*)d_in[6];
  const float* bv = (const float*)d_in[7];
  const float* Wo = (const float*)d_in[8];
  const float* bo = (const float*)d_in[9];
  float* z = (float*)d_out;

  // ws layout: ov (B*C*T floats = 7.86 MB) | WcT (256 KiB) | bc (1 KiB)
  float* ov  = (float*)d_ws;
  float* WcT = ov + (size_t)NROWS * T_DIM;
  float* bc  = WcT + C_DIM * C_DIM;

  make_wc<<<dim3(C_DIM), dim3(C_DIM), 0, stream>>>(Wo, Wv, bv, bo, WcT, bc);

  ov_kernel<<<dim3(B_DIM, C_DIM / CTILE), dim3(256), 0, stream>>>(y, WcT, bc, ov);

  add_kernel<<<dim3(ABLOCKS), dim3(ATHREADS), 0, stream>>>(x, ov, z);
}